// Round 7
// baseline (560.695 us; speedup 1.0000x reference)
//
#include <hip/hip_runtime.h>
#include <stdint.h>

#define B_   8
#define S_   1024
#define D_   1024
#define H_   16
#define DH_  64
#define N3_  3072
#define BH_  128

typedef __attribute__((ext_vector_type(16))) float f32x16;
typedef __attribute__((ext_vector_type(8)))  short su8;          // 8 bf16 payload (4 VGPRs)
typedef __attribute__((ext_vector_type(8)))  unsigned short u16x8;
typedef __attribute__((ext_vector_type(4)))  unsigned short u16x4;

__device__ __forceinline__ unsigned short f2bf(float f) {
    union { float f; uint32_t u; } v; v.f = f;
    uint32_t r = v.u + 0x7fffu + ((v.u >> 16) & 1u);   // RNE
    return (unsigned short)(r >> 16);
}
__device__ __forceinline__ unsigned int pk2(float a, float b) {
    return (unsigned int)f2bf(a) | ((unsigned int)f2bf(b) << 16);
}
__device__ __forceinline__ float bf2f(unsigned short u) {
    union { uint32_t u; float f; } v; v.u = (uint32_t)u << 16; return v.f;
}
__device__ __forceinline__ void mfma(f32x16& d, su8 a, su8 b) {
    d = __builtin_amdgcn_mfma_f32_32x32x16_bf16(a, b, d, 0, 0, 0);
}
// C/D layout for 32x32 MFMA: col = lane&31, row = (reg&3) + 8*(reg>>2) + 4*(lane>>5)
__device__ __forceinline__ int rof(int rg, int lb) { return (rg & 3) + 8 * (rg >> 2) + 4 * lb; }

// ---------------- kernel 1: hidden fp32 -> bf16 (linear) ----------------
__global__ __launch_bounds__(256) void cvt_hidden(const float4* __restrict__ src,
                                                  u16x4* __restrict__ dst) {
    int i = blockIdx.x * 256 + threadIdx.x;
    float4 v = src[i];
    u16x4 o;
    o[0] = f2bf(v.x); o[1] = f2bf(v.y); o[2] = f2bf(v.z); o[3] = f2bf(v.w);
    dst[i] = o;
}

// ---------------- kernel 2: W (k,n) fp32 -> Wt (n,k) bf16 ----------------
__global__ __launch_bounds__(256) void cvt_w(const float* __restrict__ W,
                                             unsigned short* __restrict__ Wt) {
    int t = blockIdx.x * 256 + threadIdx.x;      // 786432 threads
    int n = t % N3_;
    int k0 = (t / N3_) * 4;
    u16x4 o;
    o[0] = f2bf(W[(size_t)(k0 + 0) * N3_ + n]);
    o[1] = f2bf(W[(size_t)(k0 + 1) * N3_ + n]);
    o[2] = f2bf(W[(size_t)(k0 + 2) * N3_ + n]);
    o[3] = f2bf(W[(size_t)(k0 + 3) * N3_ + n]);
    *(u16x4*)(Wt + (size_t)n * 1024 + k0) = o;
}

// ---------------- kernel 2b: dist_emb fp32 -> bf16 (2047x64, row 2047 = pad) --
__global__ __launch_bounds__(256) void cvt_e(const float* __restrict__ de,
                                             unsigned short* __restrict__ Ebf) {
    int i = blockIdx.x * 256 + threadIdx.x;      // grid 512 -> 131072 threads
    if (i < 2047 * 64) Ebf[i] = f2bf(de[i]);
}

// ---------------- kernel 3: QKV GEMM (8192x3072x1024 bf16) ----------------
__global__ __launch_bounds__(256, 2) void gemm_qkv(
    const unsigned short* __restrict__ Ah, const unsigned short* __restrict__ Wt,
    const float* __restrict__ bias, unsigned short* __restrict__ Qw,
    unsigned short* __restrict__ Kw, unsigned short* __restrict__ Vtw) {
    __shared__ unsigned short Asm[2][128 * 64];
    __shared__ unsigned short Bsm[2][128 * 64];
    int tid = threadIdx.x;
    int m0 = (blockIdx.x / 24) * 128;
    int n0 = (blockIdx.x % 24) * 128;
    int w = tid >> 6, lane = tid & 63, li = lane & 31, lb = lane >> 5;
    int wm = w >> 1, wn = w & 1;

    f32x16 acc[2][2];
#pragma unroll
    for (int a = 0; a < 2; ++a)
#pragma unroll
        for (int b = 0; b < 2; ++b)
#pragma unroll
            for (int r = 0; r < 16; ++r) acc[a][b][r] = 0.f;

    int rw[4], ko[4], ls[4];
#pragma unroll
    for (int it = 0; it < 4; ++it) {
        int c = tid + it * 256;
        rw[it] = c >> 3;
        ko[it] = (c & 7) * 8;
        ls[it] = rw[it] * 64 + (ko[it] ^ ((rw[it] & 7) << 3));
    }

#pragma unroll
    for (int it = 0; it < 4; ++it) {
        *(u16x8*)(&Asm[0][ls[it]]) = *(const u16x8*)(Ah + (size_t)(m0 + rw[it]) * 1024 + ko[it]);
        *(u16x8*)(&Bsm[0][ls[it]]) = *(const u16x8*)(Wt + (size_t)(n0 + rw[it]) * 1024 + ko[it]);
    }
    __syncthreads();

#pragma unroll 1
    for (int t = 0; t < 16; ++t) {
        int buf = t & 1;
        u16x8 na[4], nb[4];
        if (t < 15) {
            int kb = (t + 1) * 64;
#pragma unroll
            for (int it = 0; it < 4; ++it) {
                na[it] = *(const u16x8*)(Ah + (size_t)(m0 + rw[it]) * 1024 + kb + ko[it]);
                nb[it] = *(const u16x8*)(Wt + (size_t)(n0 + rw[it]) * 1024 + kb + ko[it]);
            }
        }
#pragma unroll
        for (int kk = 0; kk < 4; ++kk) {
            su8 af[2], bf[2];
#pragma unroll
            for (int mt = 0; mt < 2; ++mt) {
                int ar = wm * 64 + mt * 32 + li;
                af[mt] = *(const su8*)(&Asm[buf][ar * 64 + ((kk * 16 + lb * 8) ^ ((ar & 7) << 3))]);
                int br = wn * 64 + mt * 32 + li;
                bf[mt] = *(const su8*)(&Bsm[buf][br * 64 + ((kk * 16 + lb * 8) ^ ((br & 7) << 3))]);
            }
            mfma(acc[0][0], af[0], bf[0]); mfma(acc[0][1], af[0], bf[1]);
            mfma(acc[1][0], af[1], bf[0]); mfma(acc[1][1], af[1], bf[1]);
        }
        if (t < 15) {
#pragma unroll
            for (int it = 0; it < 4; ++it) {
                *(u16x8*)(&Asm[buf ^ 1][ls[it]]) = na[it];
                *(u16x8*)(&Bsm[buf ^ 1][ls[it]]) = nb[it];
            }
        }
        __syncthreads();
    }

#pragma unroll
    for (int mt = 0; mt < 2; ++mt)
#pragma unroll
        for (int nt = 0; nt < 2; ++nt)
#pragma unroll
            for (int rg = 0; rg < 16; ++rg) {
                int m = m0 + wm * 64 + mt * 32 + rof(rg, lb);
                int n = n0 + wn * 64 + nt * 32 + li;
                float v = acc[mt][nt][rg] + bias[n];
                int bb = m >> 10, s = m & 1023;
                int h = n / 192, t3 = n % 192;
                size_t bh = (size_t)(bb * 16 + h);
                unsigned short bv = f2bf(v);
                if (t3 < 64)       Qw[bh * 65536 + s * 64 + t3] = bv;
                else if (t3 < 128) Kw[bh * 65536 + s * 64 + (t3 - 64)] = bv;
                else               Vtw[bh * 65536 + (size_t)(t3 - 128) * 1024 + s] = bv;
            }
}

// ---------------- kernel 4: fused attention with relative_key_query ----------------
// grid = 128 (bh) * 8 (q-blocks of 128 rows); 4 waves, wave = 32 q-rows.
// LDS 52 KB -> 3 blocks/CU. E fragments read directly from global bf16 table (L2-hot).
__global__ __launch_bounds__(256, 3) void attn(
    const unsigned short* __restrict__ Qw, const unsigned short* __restrict__ Kw,
    const unsigned short* __restrict__ Vtw, const unsigned short* __restrict__ Ebf,
    const float* __restrict__ mask, float* __restrict__ out) {
    __shared__ unsigned short Ksm[64 * 64];     // [r][d] swizzled
    __shared__ unsigned short Vsm[64 * 64];     // [d][r] swizzled
    __shared__ float Tsm[4][2176];              // per-wave diag-gather buffer
    __shared__ unsigned short Msm[1024];        // mask row (bf16)

    int tid = threadIdx.x;
    int bh = blockIdx.x >> 3, qb = blockIdx.x & 7;
    int bb = bh >> 4, h = bh & 15;
    int l0b = qb << 7;
    int w = tid >> 6, lane = tid & 63, li = lane & 31, lb = lane >> 5;
    int l0 = l0b + 32 * w;

    {   // stage mask row for this batch (bf16)
        float4 mv = ((const float4*)(mask + bb * 1024))[tid];
        u16x4 mo; mo[0] = f2bf(mv.x); mo[1] = f2bf(mv.y); mo[2] = f2bf(mv.z); mo[3] = f2bf(mv.w);
        *(u16x4*)(&Msm[tid * 4]) = mo;
    }
    su8 qf[4];
#pragma unroll
    for (int kk = 0; kk < 4; ++kk)
        qf[kk] = *(const su8*)(Qw + (size_t)(bh * 1024 + l0 + li) * 64 + lb * 8 + kk * 16);

    f32x16 cacc[2];
#pragma unroll
    for (int dt = 0; dt < 2; ++dt)
#pragma unroll
        for (int r = 0; r < 16; ++r) cacc[dt][r] = 0.f;
    float m_run = -1e30f, l_run = 0.f;

#pragma unroll 1
    for (int ss = 0; ss < 16; ++ss) {
        int r0s = ss * 64;
        int E0 = l0b - r0s + 960;
        __syncthreads();                       // previous K/V tiles fully consumed
        // stage K [64][64] and V^T [64][64] (bf16, swizzled): 2 passes each
#pragma unroll
        for (int it = 0; it < 2; ++it) {
            int c = tid + it * 256;
            int row = c >> 3, o8 = (c & 7) * 8;
            int lidx = row * 64 + (o8 ^ ((row & 7) << 3));
            u16x8 kv = *(const u16x8*)(Kw + (size_t)bh * 65536 + (size_t)(r0s + row) * 64 + o8);
            *(u16x8*)(&Ksm[lidx]) = kv;
            u16x8 vv = *(const u16x8*)(Vtw + (size_t)bh * 65536 + (size_t)row * 1024 + r0s + o8);
            *(u16x8*)(&Vsm[lidx]) = vv;
        }
        __syncthreads();

#pragma unroll
        for (int t = 0; t < 2; ++t) {
            int offw = 32 * w - 32 * t + 32;   // this wave-tile's window into E table
            su8 kf[4];
#pragma unroll
            for (int kk = 0; kk < 4; ++kk) {
                int kr = 32 * t + li;
                kf[kk] = *(const su8*)(&Ksm[kr * 64 + ((kk * 16 + lb * 8) ^ ((kr & 7) << 3))]);
            }
            f32x16 sa;
#pragma unroll
            for (int r = 0; r < 16; ++r) sa[r] = 0.f;
#pragma unroll
            for (int kk = 0; kk < 4; ++kk) mfma(sa, kf[kk], qf[kk]);   // S^T = K·Q^T

            // T_q^T = E_sub · Q^T  ->  LDS (stride 34) -> diagonal gather
#pragma unroll
            for (int ct = 0; ct < 2; ++ct) {
                f32x16 fa;
#pragma unroll
                for (int r = 0; r < 16; ++r) fa[r] = 0.f;
                const unsigned short* erow = Ebf + (size_t)(E0 + offw + ct * 32 + li) * 64 + lb * 8;
#pragma unroll
                for (int kk = 0; kk < 4; ++kk)
                    mfma(fa, *(const su8*)(erow + kk * 16), qf[kk]);
#pragma unroll
                for (int rg = 0; rg < 16; ++rg)
                    Tsm[w][(ct * 32 + rof(rg, lb)) * 34 + li] = fa[rg];
            }
#pragma unroll
            for (int rg = 0; rg < 16; ++rg) {
                int rt = rof(rg, lb);
                sa[rg] += Tsm[w][(li - rt + 31) * 34 + li];
            }
            // T_k^T = E_sub · K^T  ->  LDS (stride 33) -> diagonal gather
#pragma unroll
            for (int ct = 0; ct < 2; ++ct) {
                f32x16 fa;
#pragma unroll
                for (int r = 0; r < 16; ++r) fa[r] = 0.f;
                const unsigned short* erow = Ebf + (size_t)(E0 + offw + ct * 32 + li) * 64 + lb * 8;
#pragma unroll
                for (int kk = 0; kk < 4; ++kk)
                    mfma(fa, *(const su8*)(erow + kk * 16), kf[kk]);
#pragma unroll
                for (int rg = 0; rg < 16; ++rg)
                    Tsm[w][(ct * 32 + rof(rg, lb)) * 33 + li] = fa[rg];
            }
#pragma unroll
            for (int rg = 0; rg < 16; ++rg) {
                int rt = rof(rg, lb);
                sa[rg] += Tsm[w][(li - rt + 31) * 33 + rt];
            }
            // scale + mask + online softmax (lane owns q-row li)
#pragma unroll
            for (int rg = 0; rg < 16; ++rg)
                sa[rg] = sa[rg] * 0.125f + bf2f(Msm[r0s + 32 * t + rof(rg, lb)]);
            float cm = sa[0];
#pragma unroll
            for (int rg = 1; rg < 16; ++rg) cm = fmaxf(cm, sa[rg]);
            cm = fmaxf(cm, __shfl_xor(cm, 32));
            float mn = fmaxf(m_run, cm);
            float alpha = __expf(m_run - mn);
            float ts = 0.f;
#pragma unroll
            for (int rg = 0; rg < 16; ++rg) { sa[rg] = __expf(sa[rg] - mn); ts += sa[rg]; }
            ts += __shfl_xor(ts, 32);
            l_run = l_run * alpha + ts;
            m_run = mn;
#pragma unroll
            for (int dt = 0; dt < 2; ++dt)
#pragma unroll
                for (int r = 0; r < 16; ++r) cacc[dt][r] *= alpha;
            // P -> bf16 B-fragments (half-exchange via shfl_xor 32), PV accumulate
#pragma unroll
            for (int k2 = 0; k2 < 2; ++k2) {
                unsigned int x0 = pk2(sa[8 * k2 + 0], sa[8 * k2 + 1]);
                unsigned int x1 = pk2(sa[8 * k2 + 2], sa[8 * k2 + 3]);
                unsigned int x2 = pk2(sa[8 * k2 + 4], sa[8 * k2 + 5]);
                unsigned int x3 = pk2(sa[8 * k2 + 6], sa[8 * k2 + 7]);
                unsigned int y0 = (unsigned int)__shfl_xor((int)x0, 32);
                unsigned int y1 = (unsigned int)__shfl_xor((int)x1, 32);
                unsigned int y2 = (unsigned int)__shfl_xor((int)x2, 32);
                unsigned int y3 = (unsigned int)__shfl_xor((int)x3, 32);
                union { unsigned int u[4]; su8 s; } pu;
                pu.u[0] = lb ? y2 : x0; pu.u[1] = lb ? y3 : x1;
                pu.u[2] = lb ? x2 : y0; pu.u[3] = lb ? x3 : y1;
#pragma unroll
                for (int dt = 0; dt < 2; ++dt) {
                    int vr = dt * 32 + li;
                    int vo = 32 * t + k2 * 16 + lb * 8;
                    su8 vf = *(const su8*)(&Vsm[vr * 64 + (vo ^ ((vr & 7) << 3))]);
                    mfma(cacc[dt], vf, pu.s);   // ctx^T += V^T · P^T
                }
            }
        }
    }
    float inv = 1.0f / l_run;
    size_t obase = (size_t)(bb * 1024 + l0 + li) * 1024 + h * 64;
#pragma unroll
    for (int dt = 0; dt < 2; ++dt)
#pragma unroll
        for (int rg = 0; rg < 16; ++rg)
            out[obase + dt * 32 + rof(rg, lb)] = cacc[dt][rg] * inv;
}

extern "C" void kernel_launch(void* const* d_in, const int* in_sizes, int n_in,
                              void* d_out, int out_size, void* d_ws, size_t ws_size,
                              hipStream_t stream) {
    const float* hs   = (const float*)d_in[0];
    const float* mask = (const float*)d_in[1];
    const float* Wq   = (const float*)d_in[2];
    const float* bq   = (const float*)d_in[3];
    const float* de   = (const float*)d_in[4];
    float* out = (float*)d_out;
    char* ws = (char*)d_ws;
    unsigned short* Ah  = (unsigned short*)(ws);               // 16 MiB
    unsigned short* Wt  = (unsigned short*)(ws + 16777216);    //  6 MiB
    unsigned short* Qw  = (unsigned short*)(ws + 23068672);    // 16 MiB
    unsigned short* Kw  = (unsigned short*)(ws + 39845888);    // 16 MiB
    unsigned short* Vtw = (unsigned short*)(ws + 56623104);    // 16 MiB
    unsigned short* Ebf = (unsigned short*)(ws + 73400320);    // 256 KiB (2048 rows x 64 bf16)

    hipLaunchKernelGGL(cvt_hidden, dim3(8192), dim3(256), 0, stream,
                       (const float4*)hs, (u16x4*)Ah);
    hipLaunchKernelGGL(cvt_w, dim3(3072), dim3(256), 0, stream, Wq, Wt);
    hipLaunchKernelGGL(cvt_e, dim3(512), dim3(256), 0, stream, de, Ebf);
    hipLaunchKernelGGL(gemm_qkv, dim3(1536), dim3(256), 0, stream, Ah, Wt, bq, Qw, Kw, Vtw);
    hipLaunchKernelGGL(attn, dim3(1024), dim3(256), 0, stream, Qw, Kw, Vtw, Ebf, mask, out);
}

// Round 8
// 411.629 us; speedup vs baseline: 1.3621x; 1.3621x over previous
//
#include <hip/hip_runtime.h>
#include <stdint.h>

#define B_   8
#define S_   1024
#define D_   1024
#define H_   16
#define DH_  64
#define N3_  3072

typedef __attribute__((ext_vector_type(16))) float f32x16;
typedef __attribute__((ext_vector_type(8)))  short su8;          // 8 bf16 payload (4 VGPRs)
typedef __attribute__((ext_vector_type(8)))  unsigned short u16x8;
typedef __attribute__((ext_vector_type(4)))  unsigned short u16x4;

__device__ __forceinline__ unsigned short f2bf(float f) {
    union { float f; uint32_t u; } v; v.f = f;
    uint32_t r = v.u + 0x7fffu + ((v.u >> 16) & 1u);   // RNE
    return (unsigned short)(r >> 16);
}
__device__ __forceinline__ unsigned int pk2(float a, float b) {
    return (unsigned int)f2bf(a) | ((unsigned int)f2bf(b) << 16);
}
__device__ __forceinline__ void mfma(f32x16& d, su8 a, su8 b) {
    d = __builtin_amdgcn_mfma_f32_32x32x16_bf16(a, b, d, 0, 0, 0);
}
// C/D layout for 32x32 MFMA: col = lane&31, row = (reg&3) + 8*(reg>>2) + 4*(lane>>5)
__device__ __forceinline__ int rof(int rg, int lb) { return (rg & 3) + 8 * (rg >> 2) + 4 * lb; }

// async global->LDS, 16B per lane; lds ptr must be wave-uniform base (lane*16 added by HW)
__device__ __forceinline__ void gl_lds(const unsigned short* g, unsigned short* l) {
    __builtin_amdgcn_global_load_lds(
        (const __attribute__((address_space(1))) void*)g,
        (__attribute__((address_space(3))) void*)l, 16, 0, 0);
}

// ---------------- kernel 1: hidden fp32 -> bf16 (linear) ----------------
__global__ __launch_bounds__(256) void cvt_hidden(const float4* __restrict__ src,
                                                  u16x4* __restrict__ dst) {
    int i = blockIdx.x * 256 + threadIdx.x;
    float4 v = src[i];
    u16x4 o;
    o[0] = f2bf(v.x); o[1] = f2bf(v.y); o[2] = f2bf(v.z); o[3] = f2bf(v.w);
    dst[i] = o;
}

// ---------------- kernel 2: W (k,n) fp32 -> Wt (n,k) bf16, LDS tile transpose --
// grid = 48 (n-tiles) x 16 (k-tiles) = 768 blocks x 256 thr
__global__ __launch_bounds__(256) void cvt_w(const float* __restrict__ W,
                                             unsigned short* __restrict__ Wt) {
    __shared__ float tile[64][65];
    int bn = blockIdx.x % 48, bk = blockIdx.x / 48;
    int tr = threadIdx.x >> 4;            // 0..15
    int tc4 = (threadIdx.x & 15) * 4;     // 0..60
#pragma unroll
    for (int p = 0; p < 4; ++p) {
        int r = p * 16 + tr;              // k-row in tile
        float4 v = *(const float4*)(W + (size_t)(bk * 64 + r) * N3_ + bn * 64 + tc4);
        tile[r][tc4] = v.x; tile[r][tc4 + 1] = v.y; tile[r][tc4 + 2] = v.z; tile[r][tc4 + 3] = v.w;
    }
    __syncthreads();
#pragma unroll
    for (int p = 0; p < 4; ++p) {
        int nr = p * 16 + tr;             // n-row in tile
        u16x4 o;
        o[0] = f2bf(tile[tc4 + 0][nr]); o[1] = f2bf(tile[tc4 + 1][nr]);
        o[2] = f2bf(tile[tc4 + 2][nr]); o[3] = f2bf(tile[tc4 + 3][nr]);
        *(u16x4*)(Wt + (size_t)(bn * 64 + nr) * 1024 + bk * 64 + tc4) = o;
    }
}

// ---------------- kernel 3: QKV GEMM (8192x3072x1024 bf16), global_load_lds ----
// linear LDS dest + inverse-swizzled per-lane source == old swizzled layout (rule #21)
__global__ __launch_bounds__(256, 2) void gemm_qkv(
    const unsigned short* __restrict__ Ah, const unsigned short* __restrict__ Wt,
    const float* __restrict__ bias, unsigned short* __restrict__ Qw,
    unsigned short* __restrict__ Kw, unsigned short* __restrict__ Vtw) {
    __shared__ unsigned short Asm[2][128 * 64];
    __shared__ unsigned short Bsm[2][128 * 64];
    int tid = threadIdx.x;
    int m0 = (blockIdx.x / 24) * 128;
    int n0 = (blockIdx.x % 24) * 128;
    int w = tid >> 6, lane = tid & 63, li = lane & 31, lb = lane >> 5;
    int wm = w >> 1, wn = w & 1;

    f32x16 acc[2][2];
#pragma unroll
    for (int a = 0; a < 2; ++a)
#pragma unroll
        for (int b = 0; b < 2; ++b)
#pragma unroll
            for (int r = 0; r < 16; ++r) acc[a][b][r] = 0.f;

    int row[4], scol[4], lbase[4];
#pragma unroll
    for (int it = 0; it < 4; ++it) {
        int c = tid + it * 256;
        row[it]  = c >> 3;                                    // 0..127
        scol[it] = ((c & 7) * 8) ^ ((row[it] & 7) << 3);      // inverse-swizzled source col
        lbase[it] = it * 2048 + ((tid >> 6) << 9);            // wave-uniform LDS elem base
    }

    // prologue: stage k-chunk 0
#pragma unroll
    for (int it = 0; it < 4; ++it) {
        gl_lds(Ah + (size_t)(m0 + row[it]) * 1024 + scol[it], &Asm[0][lbase[it]]);
        gl_lds(Wt + (size_t)(n0 + row[it]) * 1024 + scol[it], &Bsm[0][lbase[it]]);
    }
    __syncthreads();

#pragma unroll 1
    for (int t = 0; t < 16; ++t) {
        int buf = t & 1;
        if (t < 15) {   // async loads for next chunk; fly under the MFMA phase
            int kb = (t + 1) * 64;
#pragma unroll
            for (int it = 0; it < 4; ++it) {
                gl_lds(Ah + (size_t)(m0 + row[it]) * 1024 + kb + scol[it], &Asm[buf ^ 1][lbase[it]]);
                gl_lds(Wt + (size_t)(n0 + row[it]) * 1024 + kb + scol[it], &Bsm[buf ^ 1][lbase[it]]);
            }
        }
#pragma unroll
        for (int kk = 0; kk < 4; ++kk) {
            su8 af[2], bf[2];
#pragma unroll
            for (int mt = 0; mt < 2; ++mt) {
                int ar = wm * 64 + mt * 32 + li;
                af[mt] = *(const su8*)(&Asm[buf][ar * 64 + ((kk * 16 + lb * 8) ^ ((ar & 7) << 3))]);
                int br = wn * 64 + mt * 32 + li;
                bf[mt] = *(const su8*)(&Bsm[buf][br * 64 + ((kk * 16 + lb * 8) ^ ((br & 7) << 3))]);
            }
            mfma(acc[0][0], af[0], bf[0]); mfma(acc[0][1], af[0], bf[1]);
            mfma(acc[1][0], af[1], bf[0]); mfma(acc[1][1], af[1], bf[1]);
        }
        __syncthreads();   // drains vmcnt: next buf ready, this buf free
    }

    // epilogue: bias, split into per-head-interleaved Q / K / V^T bf16
#pragma unroll
    for (int mt = 0; mt < 2; ++mt)
#pragma unroll
        for (int nt = 0; nt < 2; ++nt)
#pragma unroll
            for (int rg = 0; rg < 16; ++rg) {
                int m = m0 + wm * 64 + mt * 32 + rof(rg, lb);
                int n = n0 + wn * 64 + nt * 32 + li;
                float v = acc[mt][nt][rg] + bias[n];
                int bb = m >> 10, s = m & 1023;
                int h = n / 192, t3 = n % 192;
                size_t bh = (size_t)(bb * 16 + h);
                unsigned short bv = f2bf(v);
                if (t3 < 64)       Qw[bh * 65536 + s * 64 + t3] = bv;
                else if (t3 < 128) Kw[bh * 65536 + s * 64 + (t3 - 64)] = bv;
                else               Vtw[bh * 65536 + (size_t)(t3 - 128) * 1024 + s] = bv;
            }
}

// ---------------- kernel 4: fused attention (round-6 structure + T14 prefetch) --
// grid = 128 (bh) * 8 (q-blocks of 128 rows); 4 waves, wave = 32 q-rows.
__global__ __launch_bounds__(256, 2) void attn(
    const unsigned short* __restrict__ Qw, const unsigned short* __restrict__ Kw,
    const unsigned short* __restrict__ Vtw, const float* __restrict__ dist,
    const float* __restrict__ mask, float* __restrict__ out) {
    __shared__ unsigned short Ksm[64 * 64];     // [r][d] swizzled
    __shared__ unsigned short Vsm[64 * 64];     // [d][r] swizzled
    __shared__ unsigned short Esm[192 * 64];    // E slab [slabrow][d] swizzled
    __shared__ float Tsm[4][2176];              // per-wave diag-gather buffer
    __shared__ float Msm[1024];                 // mask row

    int tid = threadIdx.x;
    int bh = blockIdx.x >> 3, qb = blockIdx.x & 7;
    int bb = bh >> 4, h = bh & 15;
    int l0b = qb << 7;
    int w = tid >> 6, lane = tid & 63, li = lane & 31, lb = lane >> 5;
    int l0 = l0b + 32 * w;

    {   // stage mask row for this batch
        const float4* mp = (const float4*)(mask + bb * 1024);
        ((float4*)Msm)[tid] = mp[tid];
    }
    su8 qf[4];
#pragma unroll
    for (int kk = 0; kk < 4; ++kk)
        qf[kk] = *(const su8*)(Qw + (size_t)(bh * 1024 + l0 + li) * 64 + lb * 8 + kk * 16);

    f32x16 cacc[2];
#pragma unroll
    for (int dt = 0; dt < 2; ++dt)
#pragma unroll
        for (int r = 0; r < 16; ++r) cacc[dt][r] = 0.f;
    float m_run = -1e30f, l_run = 0.f;

    // T14 prefetch registers (issued one tile ahead; written to LDS after barrier)
    u16x8 kpre[2], vpre[2];
    float4 ep[12];
    int pc_row[6], pc_o8[6];
#pragma unroll
    for (int it = 0; it < 6; ++it) {
        int c = tid + it * 256;
        pc_row[it] = c >> 3; pc_o8[it] = (c & 7) * 8;
    }
    {   // prologue: issue loads for ss = 0
        int E0 = l0b + 960;
#pragma unroll
        for (int it = 0; it < 2; ++it) {
            int row = pc_row[it], o8 = pc_o8[it];
            kpre[it] = *(const u16x8*)(Kw + (size_t)bh * 65536 + (size_t)row * 64 + o8);
            vpre[it] = *(const u16x8*)(Vtw + (size_t)bh * 65536 + (size_t)row * 1024 + o8);
        }
#pragma unroll
        for (int it = 0; it < 6; ++it) {
            int dr = E0 + pc_row[it]; if (dr > 2046) dr = 2046;
            const float* epp = dist + (size_t)dr * 64 + pc_o8[it];
            ep[2 * it]     = *(const float4*)epp;
            ep[2 * it + 1] = *(const float4*)(epp + 4);
        }
    }

#pragma unroll 1
    for (int ss = 0; ss < 16; ++ss) {
        int r0s = ss * 64;
        __syncthreads();                       // previous tiles fully consumed
        // write phase: staged regs -> LDS (swizzled)
#pragma unroll
        for (int it = 0; it < 2; ++it) {
            int row = pc_row[it], o8 = pc_o8[it];
            int lidx = row * 64 + (o8 ^ ((row & 7) << 3));
            *(u16x8*)(&Ksm[lidx]) = kpre[it];
            *(u16x8*)(&Vsm[lidx]) = vpre[it];
        }
#pragma unroll
        for (int it = 0; it < 6; ++it) {
            int row = pc_row[it], o8 = pc_o8[it];
            float4 e0 = ep[2 * it], e1 = ep[2 * it + 1];
            u16x8 ev;
            ev[0] = f2bf(e0.x); ev[1] = f2bf(e0.y); ev[2] = f2bf(e0.z); ev[3] = f2bf(e0.w);
            ev[4] = f2bf(e1.x); ev[5] = f2bf(e1.y); ev[6] = f2bf(e1.z); ev[7] = f2bf(e1.w);
            *(u16x8*)(&Esm[row * 64 + (o8 ^ ((row & 7) << 3))]) = ev;
        }
        __syncthreads();
        if (ss < 15) {   // issue next tile's loads; latency hides under compute below
            int r0n = r0s + 64;
            int E0n = l0b - r0n + 960;
#pragma unroll
            for (int it = 0; it < 2; ++it) {
                int row = pc_row[it], o8 = pc_o8[it];
                kpre[it] = *(const u16x8*)(Kw + (size_t)bh * 65536 + (size_t)(r0n + row) * 64 + o8);
                vpre[it] = *(const u16x8*)(Vtw + (size_t)bh * 65536 + (size_t)row * 1024 + r0n + o8);
            }
#pragma unroll
            for (int it = 0; it < 6; ++it) {
                int dr = E0n + pc_row[it]; if (dr > 2046) dr = 2046; if (dr < 0) dr = 0;
                const float* epp = dist + (size_t)dr * 64 + pc_o8[it];
                ep[2 * it]     = *(const float4*)epp;
                ep[2 * it + 1] = *(const float4*)(epp + 4);
            }
        }

#pragma unroll
        for (int t = 0; t < 2; ++t) {
            int offw = 32 * w - 32 * t + 32;   // this wave-tile's window into E slab
            su8 kf[4];
#pragma unroll
            for (int kk = 0; kk < 4; ++kk) {
                int kr = 32 * t + li;
                kf[kk] = *(const su8*)(&Ksm[kr * 64 + ((kk * 16 + lb * 8) ^ ((kr & 7) << 3))]);
            }
            f32x16 sa;
#pragma unroll
            for (int r = 0; r < 16; ++r) sa[r] = 0.f;
#pragma unroll
            for (int kk = 0; kk < 4; ++kk) mfma(sa, kf[kk], qf[kk]);   // S^T = K·Q^T

            // T_q^T = E_sub · Q^T  ->  LDS (stride 34) -> diagonal gather
#pragma unroll
            for (int ct = 0; ct < 2; ++ct) {
                f32x16 fa;
#pragma unroll
                for (int r = 0; r < 16; ++r) fa[r] = 0.f;
#pragma unroll
                for (int kk = 0; kk < 4; ++kk) {
                    int er = offw + ct * 32 + li;
                    su8 ef = *(const su8*)(&Esm[er * 64 + ((kk * 16 + lb * 8) ^ ((er & 7) << 3))]);
                    mfma(fa, ef, qf[kk]);
                }
#pragma unroll
                for (int rg = 0; rg < 16; ++rg)
                    Tsm[w][(ct * 32 + rof(rg, lb)) * 34 + li] = fa[rg];
            }
#pragma unroll
            for (int rg = 0; rg < 16; ++rg) {
                int rt = rof(rg, lb);
                sa[rg] += Tsm[w][(li - rt + 31) * 34 + li];
            }
            // T_k^T = E_sub · K^T  ->  LDS (stride 33) -> diagonal gather
#pragma unroll
            for (int ct = 0; ct < 2; ++ct) {
                f32x16 fa;
#pragma unroll
                for (int r = 0; r < 16; ++r) fa[r] = 0.f;
#pragma unroll
                for (int kk = 0; kk < 4; ++kk) {
                    int er = offw + ct * 32 + li;
                    su8 ef = *(const su8*)(&Esm[er * 64 + ((kk * 16 + lb * 8) ^ ((er & 7) << 3))]);
                    mfma(fa, ef, kf[kk]);
                }
#pragma unroll
                for (int rg = 0; rg < 16; ++rg)
                    Tsm[w][(ct * 32 + rof(rg, lb)) * 33 + li] = fa[rg];
            }
#pragma unroll
            for (int rg = 0; rg < 16; ++rg) {
                int rt = rof(rg, lb);
                sa[rg] += Tsm[w][(li - rt + 31) * 33 + rt];
            }
            // scale + mask + online softmax (lane owns q-row li)
#pragma unroll
            for (int rg = 0; rg < 16; ++rg)
                sa[rg] = sa[rg] * 0.125f + Msm[r0s + 32 * t + rof(rg, lb)];
            float cm = sa[0];
#pragma unroll
            for (int rg = 1; rg < 16; ++rg) cm = fmaxf(cm, sa[rg]);
            cm = fmaxf(cm, __shfl_xor(cm, 32));
            float mn = fmaxf(m_run, cm);
            float alpha = __expf(m_run - mn);
            float ts = 0.f;
#pragma unroll
            for (int rg = 0; rg < 16; ++rg) { sa[rg] = __expf(sa[rg] - mn); ts += sa[rg]; }
            ts += __shfl_xor(ts, 32);
            l_run = l_run * alpha + ts;
            m_run = mn;
#pragma unroll
            for (int dt = 0; dt < 2; ++dt)
#pragma unroll
                for (int r = 0; r < 16; ++r) cacc[dt][r] *= alpha;
            // P -> bf16 B-fragments (half-exchange via shfl_xor 32), PV accumulate
#pragma unroll
            for (int k2 = 0; k2 < 2; ++k2) {
                unsigned int x0 = pk2(sa[8 * k2 + 0], sa[8 * k2 + 1]);
                unsigned int x1 = pk2(sa[8 * k2 + 2], sa[8 * k2 + 3]);
                unsigned int x2 = pk2(sa[8 * k2 + 4], sa[8 * k2 + 5]);
                unsigned int x3 = pk2(sa[8 * k2 + 6], sa[8 * k2 + 7]);
                unsigned int y0 = (unsigned int)__shfl_xor((int)x0, 32);
                unsigned int y1 = (unsigned int)__shfl_xor((int)x1, 32);
                unsigned int y2 = (unsigned int)__shfl_xor((int)x2, 32);
                unsigned int y3 = (unsigned int)__shfl_xor((int)x3, 32);
                union { unsigned int u[4]; su8 s; } pu;
                pu.u[0] = lb ? y2 : x0; pu.u[1] = lb ? y3 : x1;
                pu.u[2] = lb ? x2 : y0; pu.u[3] = lb ? x3 : y1;
#pragma unroll
                for (int dt = 0; dt < 2; ++dt) {
                    int vr = dt * 32 + li;
                    int vo = 32 * t + k2 * 16 + lb * 8;
                    su8 vf = *(const su8*)(&Vsm[vr * 64 + (vo ^ ((vr & 7) << 3))]);
                    mfma(cacc[dt], vf, pu.s);   // ctx^T += V^T · P^T
                }
            }
        }
    }
    float inv = 1.0f / l_run;
    size_t obase = (size_t)(bb * 1024 + l0 + li) * 1024 + h * 64;
#pragma unroll
    for (int dt = 0; dt < 2; ++dt)
#pragma unroll
        for (int rg = 0; rg < 16; ++rg)
            out[obase + dt * 32 + rof(rg, lb)] = cacc[dt][rg] * inv;
}

extern "C" void kernel_launch(void* const* d_in, const int* in_sizes, int n_in,
                              void* d_out, int out_size, void* d_ws, size_t ws_size,
                              hipStream_t stream) {
    const float* hs   = (const float*)d_in[0];
    const float* mask = (const float*)d_in[1];
    const float* Wq   = (const float*)d_in[2];
    const float* bq   = (const float*)d_in[3];
    const float* de   = (const float*)d_in[4];
    float* out = (float*)d_out;
    char* ws = (char*)d_ws;
    unsigned short* Ah  = (unsigned short*)(ws);               // 16 MiB
    unsigned short* Wt  = (unsigned short*)(ws + 16777216);    //  6 MiB
    unsigned short* Qw  = (unsigned short*)(ws + 23068672);    // 16 MiB
    unsigned short* Kw  = (unsigned short*)(ws + 39845888);    // 16 MiB
    unsigned short* Vtw = (unsigned short*)(ws + 56623104);    // 16 MiB

    hipLaunchKernelGGL(cvt_hidden, dim3(8192), dim3(256), 0, stream,
                       (const float4*)hs, (u16x4*)Ah);
    hipLaunchKernelGGL(cvt_w, dim3(768), dim3(256), 0, stream, Wq, Wt);
    hipLaunchKernelGGL(gemm_qkv, dim3(1536), dim3(256), 0, stream, Ah, Wt, bq, Qw, Kw, Vtw);
    hipLaunchKernelGGL(attn, dim3(1024), dim3(256), 0, stream, Qw, Kw, Vtw, de, mask, out);
}